// Round 6
// baseline (413.690 us; speedup 1.0000x reference)
//
#include <hip/hip_runtime.h>
#include <math.h>

#define BB 8
#define NN 2048
#define FIN 128
#define FOUT 64
#define TI 8
#define TJ 512
#define NTILE (NN / TJ)

__device__ __forceinline__ float fast_tanh(float x) {
    float e = __expf(2.f * x);
    return 1.f - 2.f / (e + 1.f);
}

// K1: h = x @ W, f1 = h.a1, f2 = h.a2. Block: 16 rows, W staged in LDS.
__global__ __launch_bounds__(256, 2) void gat_k1(const float* __restrict__ x,
                                                 const float* __restrict__ W,
                                                 const float* __restrict__ a,
                                                 float* __restrict__ h,
                                                 float* __restrict__ f1,
                                                 float* __restrict__ f2) {
    __shared__ __attribute__((aligned(16))) float Wl[FIN][FOUT];  // 32 KB
    __shared__ __attribute__((aligned(16))) float xs[16][FIN];    // 8 KB
    int t = threadIdx.x;

    const float4* W4 = (const float4*)W;
    float4* Wl4 = (float4*)&Wl[0][0];
#pragma unroll
    for (int kk = 0; kk < 8; ++kk) Wl4[t + 256 * kk] = W4[t + 256 * kk];

    size_t row0 = (size_t)blockIdx.x * 16;
    const float4* x4 = (const float4*)(x + row0 * FIN);
    float4* xs4 = (float4*)&xs[0][0];
#pragma unroll
    for (int kk = 0; kk < 2; ++kk) xs4[t + 256 * kk] = x4[t + 256 * kk];
    __syncthreads();

    int c = t & 63;
    int rq = t >> 6;
    float acc[4] = {0.f, 0.f, 0.f, 0.f};
#pragma unroll 8
    for (int k = 0; k < FIN; ++k) {
        float wv = Wl[k][c];
        acc[0] = fmaf(xs[rq][k], wv, acc[0]);
        acc[1] = fmaf(xs[rq + 4][k], wv, acc[1]);
        acc[2] = fmaf(xs[rq + 8][k], wv, acc[2]);
        acc[3] = fmaf(xs[rq + 12][k], wv, acc[3]);
    }
    float a1c = a[c], a2c = a[FOUT + c];
#pragma unroll
    for (int m = 0; m < 4; ++m) {
        size_t bn = row0 + rq + 4 * m;
        h[bn * FOUT + c] = acc[m];
        float p1 = acc[m] * a1c;
        float p2 = acc[m] * a2c;
#pragma unroll
        for (int off = 32; off > 0; off >>= 1) {
            p1 += __shfl_down(p1, off, 64);
            p2 += __shfl_down(p2, off, 64);
        }
        if (c == 0) { f1[bn] = p1; f2[bn] = p2; }
    }
}

// K2: R2/R5 hot-loop structure (2 syncs/tile, no register prefetch —
// R3/R4 one-sync + reg-prefetch spilled acc to scratch: GB-scale
// FETCH/WRITE, 4-14x regression. Do not reintroduce.)
// R6 deltas: 2D grid restored (R5's 1D XCD swizzle broke adj dispatch
// locality: hbm eff 1103->810 GB/s, k2 135->159 us) and
// __launch_bounds__(256,6): VGPR cap ~84 >= 64 demand, LDS 25KB*6=150KB
// -> 6 blocks/CU (was 4).
__global__ __launch_bounds__(256, 6) void gat_k2(const int* __restrict__ adj,
                                                 const float* __restrict__ h,
                                                 const float* __restrict__ f1,
                                                 const float* __restrict__ f2,
                                                 float* __restrict__ out) {
    __shared__ __attribute__((aligned(16))) float pbuf[TI][TJ];   // 16 KB
    __shared__ __attribute__((aligned(16))) float f2s[NN];        // 8 KB
    __shared__ float f1s[TI];
    __shared__ float srow[TI][2];   // per-row rowsum partials (2 waves/row)

    int t = threadIdx.x;
    int b = blockIdx.y;
    int i0 = blockIdx.x * TI;

    const float* f2b = f2 + (size_t)b * NN;
#pragma unroll
    for (int kk = 0; kk < 2; ++kk)
        ((float4*)f2s)[t + 256 * kk] = ((const float4*)f2b)[t + 256 * kk];
    if (t < TI) f1s[t] = f1[(size_t)b * NN + i0 + t];
    __syncthreads();

    const int* adjbase = adj + ((size_t)b * NN + (size_t)i0) * NN;
    const float* hb = h + (size_t)b * NN * FOUT;

    int cq = t & 15;     // column quad 0..15
    int jp = t >> 4;     // j partition 0..15

    float acc[TI][4];
#pragma unroll
    for (int i = 0; i < TI; ++i)
        acc[i][0] = acc[i][1] = acc[i][2] = acc[i][3] = 0.f;
    float ps[4] = {0.f, 0.f, 0.f, 0.f};

    for (int tile = 0; tile < NTILE; ++tile) {
        int j0 = tile * TJ;
        // ---- p-phase: mask -> tanh -> exp, straight into LDS ----
#pragma unroll
        for (int kk = 0; kk < 4; ++kk) {
            int g = t + 256 * kk;
            int row = g >> 7;        // wave-uniform
            int j4 = g & 127;
            int4 av = ((const int4*)(adjbase + (size_t)row * NN + j0))[j4];
            float4 fv = ((const float4*)(f2s + j0))[j4];
            float f1i = f1s[row];
            float4 p;
            p.x = (av.x > 0) ? __expf(fast_tanh(f1i + fv.x)) : 0.f;
            p.y = (av.y > 0) ? __expf(fast_tanh(f1i + fv.y)) : 0.f;
            p.z = (av.z > 0) ? __expf(fast_tanh(f1i + fv.z)) : 0.f;
            p.w = (av.w > 0) ? __expf(fast_tanh(f1i + fv.w)) : 0.f;
            ((float4*)pbuf[row])[j4] = p;
            ps[kk] += p.x + p.y + p.z + p.w;
        }
        __syncthreads();
        // ---- PV phase ----
        for (int k = 0; k < TJ / 64; ++k) {
            int g4 = jp + 16 * k;
            const float* hp = hb + (size_t)(j0 + 4 * g4) * FOUT + cq * 4;
            float4 hv0 = *(const float4*)(hp);
            float4 hv1 = *(const float4*)(hp + FOUT);
            float4 hv2 = *(const float4*)(hp + 2 * FOUT);
            float4 hv3 = *(const float4*)(hp + 3 * FOUT);
#pragma unroll
            for (int i = 0; i < TI; ++i) {
                float4 p4 = ((float4*)pbuf[i])[g4];
                acc[i][0] = fmaf(p4.x, hv0.x, acc[i][0]);
                acc[i][1] = fmaf(p4.x, hv0.y, acc[i][1]);
                acc[i][2] = fmaf(p4.x, hv0.z, acc[i][2]);
                acc[i][3] = fmaf(p4.x, hv0.w, acc[i][3]);
                acc[i][0] = fmaf(p4.y, hv1.x, acc[i][0]);
                acc[i][1] = fmaf(p4.y, hv1.y, acc[i][1]);
                acc[i][2] = fmaf(p4.y, hv1.z, acc[i][2]);
                acc[i][3] = fmaf(p4.y, hv1.w, acc[i][3]);
                acc[i][0] = fmaf(p4.z, hv2.x, acc[i][0]);
                acc[i][1] = fmaf(p4.z, hv2.y, acc[i][1]);
                acc[i][2] = fmaf(p4.z, hv2.z, acc[i][2]);
                acc[i][3] = fmaf(p4.z, hv2.w, acc[i][3]);
                acc[i][0] = fmaf(p4.w, hv3.x, acc[i][0]);
                acc[i][1] = fmaf(p4.w, hv3.y, acc[i][1]);
                acc[i][2] = fmaf(p4.w, hv3.z, acc[i][2]);
                acc[i][3] = fmaf(p4.w, hv3.w, acc[i][3]);
            }
        }
        __syncthreads();
    }

    int w = t >> 6;
    int lane = t & 63;
    // ---- rowsum: in-wave reduce; each wave's ps[kk] belongs to one row ----
#pragma unroll
    for (int kk = 0; kk < 4; ++kk) {
        float s = ps[kk];
#pragma unroll
        for (int off = 32; off > 0; off >>= 1) s += __shfl_down(s, off, 64);
        if (lane == 0) srow[2 * kk + (w >> 1)][w & 1] = s;
    }
    // ---- acc: wave-internal reduce over this wave's 4 jp partitions ----
#pragma unroll
    for (int i = 0; i < TI; ++i)
#pragma unroll
        for (int q = 0; q < 4; ++q) {
            float v = acc[i][q];
            v += __shfl_down(v, 32, 64);
            v += __shfl_down(v, 16, 64);
            acc[i][q] = v;
        }
    float* wred = &pbuf[0][0];   // [4][TI][FOUT] = 8 KB alias (post-PV)
    if (lane < 16) {
#pragma unroll
        for (int i = 0; i < TI; ++i)
            *(float4*)(wred + ((size_t)(w * TI + i) * FOUT) + lane * 4) =
                make_float4(acc[i][0], acc[i][1], acc[i][2], acc[i][3]);
    }
    __syncthreads();
    // ---- epilogue: normalize + elu, coalesced stores ----
    float* ob = out + ((size_t)b * NN + (size_t)i0) * FOUT;
#pragma unroll
    for (int u = 0; u < 2; ++u) {
        int oo = t + 256 * u;
        int i = oo >> 6;
        int c = oo & 63;
        float s = (wred[(0 * TI + i) * FOUT + c] + wred[(1 * TI + i) * FOUT + c] +
                   wred[(2 * TI + i) * FOUT + c] + wred[(3 * TI + i) * FOUT + c]) /
                  (srow[i][0] + srow[i][1]);
        ob[(size_t)i * FOUT + c] = (s > 0.f) ? s : expm1f(s);
    }
}

extern "C" void kernel_launch(void* const* d_in, const int* in_sizes, int n_in,
                              void* d_out, int out_size, void* d_ws, size_t ws_size,
                              hipStream_t stream) {
    const float* x   = (const float*)d_in[0];   // [B,N,128]
    const int*   adj = (const int*)d_in[1];     // [B,N,N]
    const float* W   = (const float*)d_in[2];   // [128,64]
    const float* a   = (const float*)d_in[3];   // [128,1]
    float* out = (float*)d_out;                 // [B,N,64]

    float* h  = (float*)d_ws;                         // B*N*64
    float* f1 = h + (size_t)BB * NN * FOUT;           // B*N
    float* f2 = f1 + (size_t)BB * NN;                 // B*N

    gat_k1<<<dim3(BB * NN / 16), dim3(256), 0, stream>>>(x, W, a, h, f1, f2);
    gat_k2<<<dim3(NN / TI, BB), dim3(256), 0, stream>>>(adj, h, f1, f2, out);
}

// Round 7
// 240.645 us; speedup vs baseline: 1.7191x; 1.7191x over previous
//
#include <hip/hip_runtime.h>
#include <math.h>

#define BB 8
#define NN 2048
#define FIN 128
#define FOUT 64
#define TI 16
#define TJ 512
#define TJP (TJ + 8)      // +8 bf16 = 16B row pad: A-frag ds_read_b128 bank skew
#define NTILE (NN / TJ)   // 4

typedef short bf16x8 __attribute__((ext_vector_type(8)));
typedef float f32x4 __attribute__((ext_vector_type(4)));

__device__ __forceinline__ float fast_tanh(float x) {
    float e = __expf(2.f * x);
    return 1.f - 2.f / (e + 1.f);
}

__device__ __forceinline__ unsigned short f2bf(float x) {
    union { float f; unsigned u; } v; v.f = x;
    unsigned r = v.u + 0x7FFF + ((v.u >> 16) & 1);   // round-to-nearest-even
    return (unsigned short)(r >> 16);
}

// K1: h = x @ W -> written as bf16 TRANSPOSED ht[b][c][n]; f1 = h.a1, f2 = h.a2.
__global__ __launch_bounds__(256, 2) void gat_k1(const float* __restrict__ x,
                                                 const float* __restrict__ W,
                                                 const float* __restrict__ a,
                                                 unsigned short* __restrict__ ht,
                                                 float* __restrict__ f1,
                                                 float* __restrict__ f2) {
    __shared__ __attribute__((aligned(16))) float Wl[FIN][FOUT];  // 32 KB
    __shared__ __attribute__((aligned(16))) float xs[16][FIN];    // 8 KB
    int t = threadIdx.x;

    const float4* W4 = (const float4*)W;
    float4* Wl4 = (float4*)&Wl[0][0];
#pragma unroll
    for (int kk = 0; kk < 8; ++kk) Wl4[t + 256 * kk] = W4[t + 256 * kk];

    size_t row0 = (size_t)blockIdx.x * 16;
    const float4* x4 = (const float4*)(x + row0 * FIN);
    float4* xs4 = (float4*)&xs[0][0];
#pragma unroll
    for (int kk = 0; kk < 2; ++kk) xs4[t + 256 * kk] = x4[t + 256 * kk];
    __syncthreads();

    int c = t & 63;
    int rq = t >> 6;
    float acc[4] = {0.f, 0.f, 0.f, 0.f};
#pragma unroll 8
    for (int k = 0; k < FIN; ++k) {
        float wv = Wl[k][c];
        acc[0] = fmaf(xs[rq][k], wv, acc[0]);
        acc[1] = fmaf(xs[rq + 4][k], wv, acc[1]);
        acc[2] = fmaf(xs[rq + 8][k], wv, acc[2]);
        acc[3] = fmaf(xs[rq + 12][k], wv, acc[3]);
    }
    float a1c = a[c], a2c = a[FOUT + c];
#pragma unroll
    for (int m = 0; m < 4; ++m) {
        size_t bn = row0 + rq + 4 * m;
        int b = (int)(bn >> 11);
        int n = (int)(bn & 2047);
        ht[((size_t)b * FOUT + c) * NN + n] = f2bf(acc[m]);
        float p1 = acc[m] * a1c;
        float p2 = acc[m] * a2c;
#pragma unroll
        for (int off = 32; off > 0; off >>= 1) {
            p1 += __shfl_down(p1, off, 64);
            p2 += __shfl_down(p2, off, 64);
        }
        if (c == 0) { f1[bn] = p1; f2[bn] = p2; }
    }
}

// K2: 16 i-rows/block. p-phase (mask->tanh->exp->bf16 P in LDS) then PV on the
// MATRIX pipe: each wave owns one 16-col tile, A=P (LDS), B=ht (global/L2),
// mfma_f32_16x16x32_bf16, f32x4 accumulator. No cross-wave acc reduction.
// (256,4): proven no-spill point — (256,5/6) spilled acc to scratch (R3/4/6).
__global__ __launch_bounds__(256, 4) void gat_k2(const int* __restrict__ adj,
                                                 const unsigned short* __restrict__ ht,
                                                 const float* __restrict__ f1,
                                                 const float* __restrict__ f2,
                                                 float* __restrict__ out) {
    __shared__ __attribute__((aligned(16))) unsigned short pb[TI][TJP];  // 16.25 KB
    __shared__ __attribute__((aligned(16))) float f2s[NN];               // 8 KB
    __shared__ float f1s[TI];
    __shared__ float srow[TI][2];

    int t = threadIdx.x;
    int b = blockIdx.y;
    int i0 = blockIdx.x * TI;

    const float* f2b = f2 + (size_t)b * NN;
#pragma unroll
    for (int kk = 0; kk < 2; ++kk)
        ((float4*)f2s)[t + 256 * kk] = ((const float4*)f2b)[t + 256 * kk];
    if (t < TI) f1s[t] = f1[(size_t)b * NN + i0 + t];
    __syncthreads();

    int lane = t & 63;
    int w = t >> 6;         // wave id -> c-tile
    int mrow = lane & 15;   // MFMA m / n index
    int quad = lane >> 4;   // MFMA k-quad

    // p-phase mapping: thread handles j4 = t&127 (float4 group), rows r0+2kk
    int j4 = t & 127;
    int r0 = t >> 7;        // wave-uniform (0 for waves 0,1; 1 for waves 2,3)

    const int* adjbase = adj + ((size_t)b * NN + (size_t)i0) * NN;
    const int* arow[8];
    float f1r[8];
#pragma unroll
    for (int kk = 0; kk < 8; ++kk) {
        arow[kk] = adjbase + (size_t)(r0 + 2 * kk) * NN + 4 * j4;
        f1r[kk] = f1s[r0 + 2 * kk];
    }

    const unsigned short* hrow =
        ht + ((size_t)b * FOUT + w * 16 + mrow) * NN + 8 * quad;
    const unsigned short* prow = &pb[mrow][8 * quad];

    f32x4 acc = {0.f, 0.f, 0.f, 0.f};
    float ps[8] = {0.f, 0.f, 0.f, 0.f, 0.f, 0.f, 0.f, 0.f};

    for (int tile = 0; tile < NTILE; ++tile) {
        int j0 = tile * TJ;
        // ---- p-phase: mask -> tanh -> exp -> bf16 into LDS ----
        float4 fv = ((const float4*)(f2s + j0))[j4];
#pragma unroll
        for (int kk = 0; kk < 8; ++kk) {
            int4 av = *(const int4*)(arow[kk] + j0);
            float f1i = f1r[kk];
            float4 p;
            p.x = (av.x > 0) ? __expf(fast_tanh(f1i + fv.x)) : 0.f;
            p.y = (av.y > 0) ? __expf(fast_tanh(f1i + fv.y)) : 0.f;
            p.z = (av.z > 0) ? __expf(fast_tanh(f1i + fv.z)) : 0.f;
            p.w = (av.w > 0) ? __expf(fast_tanh(f1i + fv.w)) : 0.f;
            ps[kk] += p.x + p.y + p.z + p.w;
            ushort4 pk;
            pk.x = f2bf(p.x); pk.y = f2bf(p.y);
            pk.z = f2bf(p.z); pk.w = f2bf(p.w);
            *(ushort4*)&pb[r0 + 2 * kk][4 * j4] = pk;
        }
        __syncthreads();
        // ---- PV on matrix pipe: 16 chunks of K=32 ----
        const unsigned short* hp = hrow + j0;
#pragma unroll 4
        for (int ch = 0; ch < TJ / 32; ++ch) {
            bf16x8 af = *(const bf16x8*)(prow + 32 * ch);
            bf16x8 bf = *(const bf16x8*)(hp + 32 * ch);
            acc = __builtin_amdgcn_mfma_f32_16x16x32_bf16(af, bf, acc, 0, 0, 0);
        }
        __syncthreads();
    }

    // ---- rowsum: in-wave reduce (each wave's ps[kk] belongs to one row) ----
#pragma unroll
    for (int kk = 0; kk < 8; ++kk) {
        float s = ps[kk];
#pragma unroll
        for (int off = 32; off > 0; off >>= 1) s += __shfl_down(s, off, 64);
        if (lane == 0) srow[2 * kk + (w >> 1)][w & 1] = s;
    }
    __syncthreads();
    // ---- epilogue: D-frag (col=lane&15, row=quad*4+reg) -> /rowsum -> elu ----
    float* ob = out + ((size_t)b * NN + (size_t)i0) * FOUT + w * 16 + mrow;
#pragma unroll
    for (int u = 0; u < 4; ++u) {
        int row = quad * 4 + u;
        float rs = srow[row][0] + srow[row][1];
        float s = acc[u] / rs;
        ob[(size_t)row * FOUT] = (s > 0.f) ? s : expm1f(s);
    }
}

extern "C" void kernel_launch(void* const* d_in, const int* in_sizes, int n_in,
                              void* d_out, int out_size, void* d_ws, size_t ws_size,
                              hipStream_t stream) {
    const float* x   = (const float*)d_in[0];   // [B,N,128]
    const int*   adj = (const int*)d_in[1];     // [B,N,N]
    const float* W   = (const float*)d_in[2];   // [128,64]
    const float* a   = (const float*)d_in[3];   // [128,1]
    float* out = (float*)d_out;                 // [B,N,64]

    unsigned short* ht = (unsigned short*)d_ws;          // [B][64][2048] bf16, 2 MB
    float* f1 = (float*)(ht + (size_t)BB * FOUT * NN);   // B*N
    float* f2 = f1 + (size_t)BB * NN;                    // B*N

    gat_k1<<<dim3(BB * NN / 16), dim3(256), 0, stream>>>(x, W, a, ht, f1, f2);
    gat_k2<<<dim3(NN / TI, BB), dim3(256), 0, stream>>>(adj, ht, f1, f2, out);
}